// Round 12
// baseline (169.426 us; speedup 1.0000x reference)
//
#include <hip/hip_runtime.h>

#define NB 32768
#define NF 256
#define H1 16
#define H2 8
#define ROWS_PER_BLOCK 1024
#define ITERS (ROWS_PER_BLOCK / 64)   // 16 (one row per lane per iter)
#define FPB 4                         // features (waves) per block
#define NT (FPB * 64)                 // 256 threads

__device__ __forceinline__ float elu_f(float v) {
    return v > 0.0f ? v : (__expf(v) - 1.0f);
}
// force a wave-uniform float into an SGPR
__device__ __forceinline__ float rfl(float v) {
    return __int_as_float(__builtin_amdgcn_readfirstlane(__float_as_int(v)));
}

// R11 compute body (SGPR W2 rows0-7 / LDS rows8-11 / VGPR rows12-15), with the
// x-load and z-store scatter replaced by LDS-transposed coalesced access:
//  - x: the block's 4 features are columns f0..f0+3 -> per 64-row slab, 16
//    lanes/wave cooperatively load float4 x[row][f0:4] (64 line-touches vs 256
//    redundant scattered ones), ds_write transposed, compute reads
//    xbuf[wave][lane] conflict-free.
//  - z: waves ds_write zbuf[row][wave] (stride-5 pad, conflict-free), writer
//    lanes emit global_store_dwordx4 per row.
//  Double-buffered x and z => ONE barrier per iteration.
__global__ __launch_bounds__(NT, 5)
void z_kernel(const float* __restrict__ x,  const float* __restrict__ W1,
              const float* __restrict__ b1, const float* __restrict__ W2,
              const float* __restrict__ b2, const float* __restrict__ W3,
              const float* __restrict__ b3, float* __restrict__ z_out) {
    const int wave = threadIdx.x >> 6;
    const int lane = threadIdx.x & 63;
    const int f0   = blockIdx.y * FPB;
    const int f    = f0 + wave;
    const int rowBase = blockIdx.x * ROWS_PER_BLOCK;

    __shared__ float lds_w2[FPB][32];        // W2 rows 8..11 per feature
    __shared__ float xbuf[2][FPB][64];       // [buf][feat-col][row]
    __shared__ float zbuf[2][64][5];         // [buf][row][feat-col + pad]

    // ---- stage W2 rows 8..11 into LDS (8 lanes x float4) ----
    if (lane < 8) {
        const float4 v = reinterpret_cast<const float4*>(W2 + f * H1 * H2 + 64)[lane];
        reinterpret_cast<float4*>(lds_w2[wave])[lane] = v;
    }

    // ---- W2 rows 0..7 -> SGPR ----
    float s_w2[8 * H2];
    {
        const float4* p = reinterpret_cast<const float4*>(W2 + f * H1 * H2);
        #pragma unroll
        for (int i = 0; i < 16; ++i) {
            float4 v = p[i];
            s_w2[4*i]   = rfl(v.x); s_w2[4*i+1] = rfl(v.y);
            s_w2[4*i+2] = rfl(v.z); s_w2[4*i+3] = rfl(v.w);
        }
    }
    // ---- W2 rows 12..15 -> per-lane VGPR (32 floats) ----
    float w2v[32];
    {
        const float4* p = reinterpret_cast<const float4*>(W2 + f * H1 * H2 + 96);
        #pragma unroll
        for (int i = 0; i < 8; ++i) {
            float4 v = p[i];
            w2v[4*i]=v.x; w2v[4*i+1]=v.y; w2v[4*i+2]=v.z; w2v[4*i+3]=v.w;
        }
    }
    // ---- W1 -> per-lane VGPR, b1 -> SGPR ----
    float w1v[H1], s_b1[H1];
    {
        const float4* pw = reinterpret_cast<const float4*>(W1 + f * H1);
        const float4* pb = reinterpret_cast<const float4*>(b1 + f * H1);
        #pragma unroll
        for (int i = 0; i < 4; ++i) {
            float4 v = pw[i];
            w1v[4*i] = v.x; w1v[4*i+1] = v.y; w1v[4*i+2] = v.z; w1v[4*i+3] = v.w;
        }
        #pragma unroll
        for (int i = 0; i < 4; ++i) {
            float4 v = pb[i];
            s_b1[4*i]   = rfl(v.x); s_b1[4*i+1] = rfl(v.y);
            s_b1[4*i+2] = rfl(v.z); s_b1[4*i+3] = rfl(v.w);
        }
    }
    // ---- b2 -> per-lane VGPR; W3, b3 -> SGPR ----
    float b2v[H2];
    {
        const float4* p = reinterpret_cast<const float4*>(b2 + f * H2);
        float4 v0 = p[0], v1 = p[1];
        b2v[0]=v0.x; b2v[1]=v0.y; b2v[2]=v0.z; b2v[3]=v0.w;
        b2v[4]=v1.x; b2v[5]=v1.y; b2v[6]=v1.z; b2v[7]=v1.w;
    }
    float s_w3[H2];
    {
        const float4* p = reinterpret_cast<const float4*>(W3 + f * H2);
        float4 v0 = p[0], v1 = p[1];
        s_w3[0]=rfl(v0.x); s_w3[1]=rfl(v0.y); s_w3[2]=rfl(v0.z); s_w3[3]=rfl(v0.w);
        s_w3[4]=rfl(v1.x); s_w3[5]=rfl(v1.y); s_w3[6]=rfl(v1.z); s_w3[7]=rfl(v1.w);
    }
    const float s_b3 = rfl(b3[f]);

    // ---- prologue: stage x slab 0 ----
    const int r16 = (lane & 15);                 // loader/writer row-in-16
    const bool io = (lane < 16);
    const int myrow = wave * 16 + r16;           // 0..63 across the block
    if (io) {
        const float4 v = *reinterpret_cast<const float4*>(
            x + (size_t)(rowBase + myrow) * NF + f0);
        xbuf[0][0][myrow] = v.x; xbuf[0][1][myrow] = v.y;
        xbuf[0][2][myrow] = v.z; xbuf[0][3][myrow] = v.w;
    }
    __syncthreads();                             // x slab 0 + lds_w2 ready

    const float* wbase = lds_w2[wave];
    int cur = 0;

    #pragma unroll 1
    for (int it = 0; it < ITERS; ++it) {
        // 1) issue coalesced load of next slab into regs (latency under compute)
        float4 xnext;
        if (io) {
            const int nit = (it + 1 < ITERS) ? it + 1 : it;
            xnext = *reinterpret_cast<const float4*>(
                x + (size_t)(rowBase + nit * 64 + myrow) * NF + f0);
        }

        // 2) my x value from LDS (conflict-free: consecutive lanes, consec banks)
        const float xv = xbuf[cur][wave][lane];

        // 3) compute (identical to R11)
        float acc[H2];
        #pragma unroll
        for (int k = 0; k < H2; ++k) acc[k] = b2v[k];

        #pragma unroll
        for (int h = 0; h < 8; ++h) {            // W2 rows 0..7: SGPR path
            const float h1 = elu_f(fmaf(xv, w1v[h], s_b1[h]));
            #pragma unroll
            for (int k = 0; k < H2; ++k)
                acc[k] = fmaf(h1, s_w2[h * H2 + k], acc[k]);
        }

        int dsoff = 0;                           // block LICM hoisting
        asm volatile("" : "+v"(dsoff));
        const float4* wp = reinterpret_cast<const float4*>(wbase + dsoff);
        #pragma unroll
        for (int h = 0; h < 4; ++h) {            // W2 rows 8..11: LDS path
            const float4 wlo = wp[2 * h];
            const float4 whi = wp[2 * h + 1];
            const float h1 = elu_f(fmaf(xv, w1v[8 + h], s_b1[8 + h]));
            acc[0] = fmaf(h1, wlo.x, acc[0]);
            acc[1] = fmaf(h1, wlo.y, acc[1]);
            acc[2] = fmaf(h1, wlo.z, acc[2]);
            acc[3] = fmaf(h1, wlo.w, acc[3]);
            acc[4] = fmaf(h1, whi.x, acc[4]);
            acc[5] = fmaf(h1, whi.y, acc[5]);
            acc[6] = fmaf(h1, whi.z, acc[6]);
            acc[7] = fmaf(h1, whi.w, acc[7]);
        }

        #pragma unroll
        for (int h = 0; h < 4; ++h) {            // W2 rows 12..15: VGPR path
            const float h1 = elu_f(fmaf(xv, w1v[12 + h], s_b1[12 + h]));
            #pragma unroll
            for (int k = 0; k < H2; ++k)
                acc[k] = fmaf(h1, w2v[h * H2 + k], acc[k]);
        }

        float z = s_b3;
        #pragma unroll
        for (int k = 0; k < H2; ++k)
            z = fmaf(elu_f(acc[k]), s_w3[k], z);

        // 4) stage z into padded LDS tile (banks (5*lane+wave)%32: conflict-free)
        zbuf[cur][lane][wave] = z;

        // 5) write next x slab into the other buffer
        if (io) {
            xbuf[cur ^ 1][0][myrow] = xnext.x; xbuf[cur ^ 1][1][myrow] = xnext.y;
            xbuf[cur ^ 1][2][myrow] = xnext.z; xbuf[cur ^ 1][3][myrow] = xnext.w;
        }

        __syncthreads();                         // z[cur] + x[cur^1] visible

        // 6) coalesced z store: one float4 per row
        if (io) {
            float4 zq;
            zq.x = zbuf[cur][myrow][0]; zq.y = zbuf[cur][myrow][1];
            zq.z = zbuf[cur][myrow][2]; zq.w = zbuf[cur][myrow][3];
            *reinterpret_cast<float4*>(
                z_out + (size_t)(rowBase + it * 64 + myrow) * NF + f0) = zq;
        }
        cur ^= 1;
    }
}

// Memory-bound epilogue: w = softplus(theta); y[row] = dot(z[row,:], w) + bias.
#define NT2 256
#define ROWS2 64
__global__ __launch_bounds__(NT2, 4)
void y_kernel(const float* __restrict__ z, const float* __restrict__ theta,
              const float* __restrict__ bias, float* __restrict__ y_out,
              float* __restrict__ w_out) {
    __shared__ __align__(16) float wls[NF];
    const int tid = threadIdx.x;
    {
        const float th = theta[tid];
        const float w  = logf(1.0f + __expf(th));
        wls[tid] = w;
        if (blockIdx.x == 0) w_out[tid] = w;
    }
    __syncthreads();
    const int wave = tid >> 6, lane = tid & 63;
    const float4 w4 = reinterpret_cast<const float4*>(wls)[lane];
    const float biasv = bias[0];
    #pragma unroll 1
    for (int r = 0; r < ROWS2 / 4; ++r) {          // 16 rows per wave
        const int row = blockIdx.x * ROWS2 + wave * (ROWS2 / 4) + r;
        const float4 zv = reinterpret_cast<const float4*>(z + row * NF)[lane];
        float s = zv.x * w4.x + zv.y * w4.y + zv.z * w4.z + zv.w * w4.w;
        #pragma unroll
        for (int o = 32; o > 0; o >>= 1) s += __shfl_down(s, o, 64);
        if (lane == 0) y_out[row] = s + biasv;
    }
}

extern "C" void kernel_launch(void* const* d_in, const int* in_sizes, int n_in,
                              void* d_out, int out_size, void* d_ws, size_t ws_size,
                              hipStream_t stream) {
    const float* x     = (const float*)d_in[0];
    const float* W1    = (const float*)d_in[1];
    const float* b1    = (const float*)d_in[2];
    const float* W2    = (const float*)d_in[3];
    const float* b2    = (const float*)d_in[4];
    const float* W3    = (const float*)d_in[5];
    const float* b3    = (const float*)d_in[6];
    const float* theta = (const float*)d_in[7];
    const float* bias  = (const float*)d_in[8];

    float* y_out = (float*)d_out;                  // [32768]
    float* w_out = y_out + NB;                     // [256]
    float* z_out = w_out + NF;                     // [32768*256]

    dim3 grid1(NB / ROWS_PER_BLOCK, NF / FPB);     // 32 x 64
    z_kernel<<<grid1, NT, 0, stream>>>(x, W1, b1, W2, b2, W3, b3, z_out);
    y_kernel<<<NB / ROWS2, NT2, 0, stream>>>(z_out, theta, bias, y_out, w_out);
}